// Round 2
// baseline (3597.183 us; speedup 1.0000x reference)
//
#include <hip/hip_runtime.h>
#include <math.h>

#define NB 4
#define NW 24
#define H 512
#define H2 1024
#define H5 2560
#define NCELL 300   // n*(n+1)/2 valid cells per batch
#define CTILE 16

// total workspace floats needed
#define NEED_FLOATS (2u*H*H5 + 2u*NB*NCELL*H + NB*NCELL + 2u*NB*NCELL*H5 + NB*NCELL*H2)
#define NEED_BYTES  ((size_t)NEED_FLOATS * 4u)

// Private fallback workspace: allocated ONCE at library load (outside
// kernel_launch, so graph capture never sees the hipMalloc). d_ws proved too
// small in round 1 (44.9MB layout corrupted adjacent harness allocations:
// first call correct, all restored calls consistently wrong).
static float* g_buf = nullptr;
__attribute__((constructor)) static void dio_alloc_ws(){
  (void)hipMalloc((void**)&g_buf, NEED_BYTES + (1u<<20));
}

__device__ __forceinline__ int coff(int l){ return l*NW - (l*(l-1))/2; }
__device__ __forceinline__ float sigm(float x){ return 1.f/(1.f+__expf(-x)); }
__device__ __forceinline__ float ftanh(float x){ return 1.f - 2.f/(__expf(2.f*x)+1.f); }

// ---- transpose Wi [2560,512] -> WiT [512,2560] (and Ws) for coalesced proj reads
__global__ void k_transpose(const float* __restrict__ Wi, const float* __restrict__ Ws,
                            float* __restrict__ WiT, float* __restrict__ WsT){
  const float* in  = blockIdx.z ? Ws  : Wi;
  float*       out = blockIdx.z ? WsT : WiT;
  __shared__ float tile[32][33];
  int tr = blockIdx.y*32, tc = blockIdx.x*32;
  int tx = threadIdx.x, ty = threadIdx.y;
  #pragma unroll
  for (int i=0;i<32;i+=8)
    tile[ty+i][tx] = in[(size_t)(tr+ty+i)*H + tc+tx];
  __syncthreads();
  #pragma unroll
  for (int i=0;i<32;i+=8)
    out[(size_t)(tc+ty+i)*H5 + tr+tx] = tile[tx][ty+i];
}

// ---- leaves: cell (i,0): H = seq[i,:512], C = seq[i,512:], S = 0
__global__ void k_leaf(const float* __restrict__ seqt, float* __restrict__ cH,
                       float* __restrict__ cC, float* __restrict__ cS){
  int tid = blockIdx.x*256 + threadIdx.x;
  if (tid >= NB*NW*H) return;
  int b = tid/(NW*H); int r = tid%(NW*H); int i = r/H; int d = r%H;
  int cell = b*NCELL + i;                 // coff(0)==0
  cH[(size_t)cell*H + d] = seqt[(size_t)(b*NW+i)*H2 + d];
  cC[(size_t)cell*H + d] = seqt[(size_t)(b*NW+i)*H2 + H + d];
  if (d==0) cS[cell] = 0.f;
}

// ---- per-cell projections for diagonal d:
//   PI = H@Wi^T + bi + ins_bias ; PS = H@Ws^T + bs ; U = [H,C]^T Wbil
// grid.x = 24 parts (0-9: PI cols, 10-19: PS cols, 20-23: U cols), grid.y = cell chunks of 16
__global__ void k_proj(const float* __restrict__ WiT, const float* __restrict__ WsT,
                       const float* __restrict__ Wbil, const float* __restrict__ bi,
                       const float* __restrict__ bs,
                       const float* __restrict__ cH, const float* __restrict__ cC,
                       float* __restrict__ cPI, float* __restrict__ cPS, float* __restrict__ cU,
                       int d, int P){
  __shared__ float As[512*CTILE];   // [k][m]
  const int t = threadIdx.x;
  const int part = blockIdx.x;
  const int m0 = blockIdx.y*CTILE;
  const int Mtot = NB*P;
  const int nm = min(CTILE, Mtot-m0);
  float acc[CTILE];
  #pragma unroll
  for (int m=0;m<CTILE;m++) acc[m]=0.f;

  int kind, j;
  if (part<10){ kind=0; j=part*256+t; }
  else if (part<20){ kind=1; j=(part-10)*256+t; }
  else { kind=2; j=(part-20)*256+t; }
  const int nsl = (kind==2)?2:1;

  for (int s=0;s<nsl;s++){
    for (int li=t; li<512*CTILE; li+=256){
      int m = li>>9, k = li&511;
      float v = 0.f;
      if (m<nm){
        int mg = m0+m; int b = mg/P, i = mg%P;
        int cell = b*NCELL + coff(d)+i;
        const float* src = (kind==2 && s==1) ? cC : cH;
        v = src[(size_t)cell*H + k];
      }
      As[k*CTILE+m] = v;
    }
    __syncthreads();
    const float* Wp; int ldw;
    if (kind==0){ Wp=WiT; ldw=H5; }
    else if (kind==1){ Wp=WsT; ldw=H5; }
    else { Wp=Wbil + (size_t)s*512*H2; ldw=H2; }
    const float4* A4 = (const float4*)As;
    for (int k=0;k<512;k++){
      float w = Wp[(size_t)k*ldw + j];
      float4 a0 = A4[k*4+0], a1 = A4[k*4+1], a2 = A4[k*4+2], a3 = A4[k*4+3];
      acc[0] +=a0.x*w; acc[1] +=a0.y*w; acc[2] +=a0.z*w; acc[3] +=a0.w*w;
      acc[4] +=a1.x*w; acc[5] +=a1.y*w; acc[6] +=a1.z*w; acc[7] +=a1.w*w;
      acc[8] +=a2.x*w; acc[9] +=a2.y*w; acc[10]+=a2.z*w; acc[11]+=a2.w*w;
      acc[12]+=a3.x*w; acc[13]+=a3.y*w; acc[14]+=a3.z*w; acc[15]+=a3.w*w;
    }
    __syncthreads();
  }
  float bias = 0.f;
  if (kind==0) bias = bi[j] + ((j>=H && j<3*H)?1.f:0.f);   // ins_bias on [H,3H)
  else if (kind==1) bias = bs[j];
  for (int m=0;m<nm;m++){
    int mg = m0+m; int b = mg/P, i = mg%P;
    int cell = b*NCELL + coff(d)+i;
    if (kind==0)      cPI[(size_t)cell*H5 + j] = acc[m]+bias;
    else if (kind==1) cPS[(size_t)cell*H5 + j] = acc[m]+bias;
    else              cU [(size_t)cell*H2 + j] = acc[m];
  }
}

// ---- combine diagonal L: one block per (b,left) span of length L+1
__global__ void k_combine(const float* __restrict__ cPI, const float* __restrict__ cPS,
                          const float* __restrict__ cU,
                          float* __restrict__ cH, float* __restrict__ cC, float* __restrict__ cS,
                          int L, int P){
  const int t = threadIdx.x;
  const int b = blockIdx.x / P;
  const int left = blockIdx.x % P;
  __shared__ float compat_s[32];
  __shared__ float wts_s[32];
  __shared__ float S_s;
  const int lane = t & 63;
  const int wv = t >> 6;
  // phase 1: compat_k = U[lcell] . [H;C][rcell] + lS + rS, waves parallel over k
  for (int k=wv; k<L; k+=4){
    int lc = b*NCELL + coff(k) + left;
    int rc = b*NCELL + coff(L-1-k) + left+k+1;
    const float* U  = cU + (size_t)lc*H2;
    const float* Hr = cH + (size_t)rc*H;
    const float* Cr = cC + (size_t)rc*H;
    float p = 0.f;
    for (int i=lane; i<H; i+=64)
      p += U[i]*Hr[i] + U[H+i]*Cr[i];
    #pragma unroll
    for (int off=32; off>0; off>>=1) p += __shfl_down(p, off);
    if (lane==0) compat_s[k] = p + cS[lc] + cS[rc];
  }
  __syncthreads();
  // phase 2: softmax over k (L<=23, serial on thread 0)
  if (t==0){
    float mx = -1e30f;
    for (int k=0;k<L;k++) mx = fmaxf(mx, compat_s[k]);
    float den = 0.f;
    for (int k=0;k<L;k++){ float e = __expf(compat_s[k]-mx); wts_s[k]=e; den+=e; }
    float inv = 1.f/den, S = 0.f;
    for (int k=0;k<L;k++){ wts_s[k]*=inv; S += wts_s[k]*compat_s[k]; }
    S_s = S;
  }
  __syncthreads();
  // phase 3: gates + weighted accumulate; thread t handles dims t and t+256
  float aH0=0.f, aH1=0.f, aC0=0.f, aC1=0.f;
  const int d0 = t, d1 = t+256;
  for (int k=0;k<L;k++){
    float wk = wts_s[k];
    int lc = b*NCELL + coff(k) + left;
    int rc = b*NCELL + coff(L-1-k) + left+k+1;
    const float* PI  = cPI + (size_t)lc*H5;
    const float* PS  = cPS + (size_t)rc*H5;
    const float* lCp = cC + (size_t)lc*H;
    const float* rCp = cC + (size_t)rc*H;
    {
      float p0 = PI[d0]     + PS[d0];
      float p1 = PI[H+d0]   + PS[H+d0];
      float p2 = PI[2*H+d0] + PS[2*H+d0];
      float p3 = PI[3*H+d0] + PS[3*H+d0];
      float p4 = PI[4*H+d0] + PS[4*H+d0];
      float mem = sigm(p1)*lCp[d0] + sigm(p2)*rCp[d0] + sigm(p0)*ftanh(p3);
      float h = sigm(p4)*ftanh(mem);
      aH0 += wk*h; aC0 += wk*mem;
    }
    {
      float p0 = PI[d1]     + PS[d1];
      float p1 = PI[H+d1]   + PS[H+d1];
      float p2 = PI[2*H+d1] + PS[2*H+d1];
      float p3 = PI[3*H+d1] + PS[3*H+d1];
      float p4 = PI[4*H+d1] + PS[4*H+d1];
      float mem = sigm(p1)*lCp[d1] + sigm(p2)*rCp[d1] + sigm(p0)*ftanh(p3);
      float h = sigm(p4)*ftanh(mem);
      aH1 += wk*h; aC1 += wk*mem;
    }
  }
  int nc = b*NCELL + coff(L) + left;
  cH[(size_t)nc*H + d0] = aH0; cH[(size_t)nc*H + d1] = aH1;
  cC[(size_t)nc*H + d0] = aC0; cC[(size_t)nc*H + d1] = aC1;
  if (t==0) cS[nc] = S_s;
}

// ---- root output: concat(H, C) of cell (0, n-1)
__global__ void k_out(const float* __restrict__ cH, const float* __restrict__ cC,
                      float* __restrict__ out){
  int tid = blockIdx.x*256+threadIdx.x;
  if (tid >= NB*H2) return;
  int b = tid>>10, d = tid&1023;
  int cell = b*NCELL + 299;   // coff(23)+0
  out[tid] = (d<H) ? cH[(size_t)cell*H + d] : cC[(size_t)cell*H + (d-H)];
}

extern "C" void kernel_launch(void* const* d_in, const int* in_sizes, int n_in,
                              void* d_out, int out_size, void* d_ws, size_t ws_size,
                              hipStream_t stream){
  const float* seqt = (const float*)d_in[0];
  const float* Wi   = (const float*)d_in[1];
  const float* bi   = (const float*)d_in[2];
  const float* Ws   = (const float*)d_in[3];
  const float* bs   = (const float*)d_in[4];
  const float* Wbil = (const float*)d_in[5];
  float* out = (float*)d_out;

  // Use d_ws only if it is provably large enough; otherwise use the private
  // ctor-allocated buffer. ws_size is constant across calls -> same path,
  // same work on every call (graph-safe).
  float* p = (ws_size >= NEED_BYTES && g_buf == nullptr) ? (float*)d_ws : g_buf;
  float* WiT = p; p += (size_t)H*H5;          // 512*2560
  float* WsT = p; p += (size_t)H*H5;
  float* cH  = p; p += (size_t)NB*NCELL*H;
  float* cC  = p; p += (size_t)NB*NCELL*H;
  float* cS  = p; p += (size_t)NB*NCELL;
  float* cPI = p; p += (size_t)NB*NCELL*H5;
  float* cPS = p; p += (size_t)NB*NCELL*H5;
  float* cU  = p; p += (size_t)NB*NCELL*H2;

  k_transpose<<<dim3(16,80,2), dim3(32,8), 0, stream>>>(Wi, Ws, WiT, WsT);
  k_leaf<<<(NB*NW*H+255)/256, 256, 0, stream>>>(seqt, cH, cC, cS);
  k_proj<<<dim3(24, (NB*NW+CTILE-1)/CTILE), 256, 0, stream>>>(
      WiT, WsT, Wbil, bi, bs, cH, cC, cPI, cPS, cU, 0, NW);
  for (int L=1; L<NW; L++){
    int P = NW - L;
    k_combine<<<NB*P, 256, 0, stream>>>(cPI, cPS, cU, cH, cC, cS, L, P);
    if (L < NW-1)
      k_proj<<<dim3(24, (NB*P+CTILE-1)/CTILE), 256, 0, stream>>>(
          WiT, WsT, Wbil, bi, bs, cH, cC, cPI, cPS, cU, L, P);
  }
  k_out<<<16, 256, 0, stream>>>(cH, cC, out);
}